// Round 4
// baseline (16826.898 us; speedup 1.0000x reference)
//
#include <hip/hip_runtime.h>

#define BB 128
#define SS 256
#define WW 20
#define WE 300
#define CE 50
#define CC 100
#define DIN 400
#define HID 512
#define Hh 256
#define TT 12
#define START_TAG 9
#define STOP_TAG 10
#define PAD_TAG 11
#define NEGV (-10000.0f)
#define BS 32768   // BB*SS
#define CH 32      // timesteps per chunk
#define NCH 8      // SS/CH
#define CR 4096    // CH*BB rows per direction per chunk
#define HGLOB_STRIDE (2 * Hh * BB)   // one parity slab: [dir][k][b]

// full-emb mode ws floats: emb 13107200 + gates 8388608 + lstm 2097152 + feats 393216
//                          + hglob 131072 + cbuf 65536 + bar 128
#define FULL_NEEDED_BYTES 96731648ull

// ---------------- Kernel A-full: embed entire sequence, each position ONCE ----------------
__global__ __launch_bounds__(256) void k_embedF(
    const int* __restrict__ widx, const int* __restrict__ cidx,
    const float* __restrict__ wtab, const float* __restrict__ ctab,
    const float* __restrict__ convw, const float* __restrict__ convb,
    float* __restrict__ emb)
{
    __shared__ __align__(16) float ce_sh[2][CE][24];
    __shared__ int cid_sh[2][WW];
    __shared__ int wid_sh[2];
    const int tid = threadIdx.x;
    const int pl0 = blockIdx.x * 2;

    int g[2];
    #pragma unroll
    for (int p = 0; p < 2; p++) {
        int pl = pl0 + p;
        int s = pl >> 7, b = pl & 127;
        g[p] = b * SS + s;
    }

    if (tid < 2 * WW) {
        int p = tid / WW, w = tid % WW;
        cid_sh[p][w] = cidx[g[p] * WW + w];
    }
    if (tid < 2) wid_sh[tid] = widx[g[tid]];
    for (int i = tid; i < 2 * CE * 24; i += 256) ((float*)ce_sh)[i] = 0.f;
    __syncthreads();

    for (int i = tid; i < 2 * WW * CE; i += 256) {
        int p = i / (WW * CE);
        int rem = i % (WW * CE);
        int w = rem / CE, ce = rem % CE;
        ce_sh[p][ce][w + 1] = ctab[cid_sh[p][w] * CE + ce];
    }
    for (int i = tid; i < 2 * WE; i += 256) {
        int p = i / WE, col = i % WE;
        emb[(size_t)(pl0 + p) * DIN + col] = wtab[(size_t)wid_sh[p] * WE + col];
    }
    __syncthreads();

    const int p = tid >> 7;
    const int cc = tid & 127;
    if (cc < CC) {
        float acc[WW];
        #pragma unroll
        for (int w = 0; w < WW; w++) acc[w] = 0.f;
        for (int ce = 0; ce < CE; ce++) {
            float row[24];
            #pragma unroll
            for (int q = 0; q < 6; q++) {
                float4 v = *(const float4*)&ce_sh[p][ce][q * 4];
                row[q * 4 + 0] = v.x; row[q * 4 + 1] = v.y;
                row[q * 4 + 2] = v.z; row[q * 4 + 3] = v.w;
            }
            float c0 = convw[(cc * CE + ce) * 3 + 0];
            float c1 = convw[(cc * CE + ce) * 3 + 1];
            float c2 = convw[(cc * CE + ce) * 3 + 2];
            #pragma unroll
            for (int w = 0; w < WW; w++)
                acc[w] += c0 * row[w] + c1 * row[w + 1] + c2 * row[w + 2];
        }
        float bb = convb[cc];
        float m = 0.f;
        #pragma unroll
        for (int w = 0; w < WW; w++) {
            float v = acc[w] + bb;
            v = v > 0.f ? v : 0.f;
            m = v > m ? v : m;
        }
        emb[(size_t)(pl0 + p) * DIN + WE + cc] = m;
    }
}

// ---------------- Kernel A-chunk: fallback (embed chunk rows, both dir ranges) ----------------
__global__ __launch_bounds__(256) void k_embedC(
    const int* __restrict__ widx, const int* __restrict__ cidx,
    const float* __restrict__ wtab, const float* __restrict__ ctab,
    const float* __restrict__ convw, const float* __restrict__ convb,
    float* __restrict__ embC, int c)
{
    __shared__ __align__(16) float ce_sh[2][CE][24];
    __shared__ int cid_sh[2][WW];
    __shared__ int wid_sh[2];
    const int tid = threadIdx.x;
    const int pl0 = blockIdx.x * 2;

    int part[2], lr[2], g[2];
    #pragma unroll
    for (int p = 0; p < 2; p++) {
        int pl = pl0 + p;
        part[p] = pl >> 12;
        lr[p] = pl & 4095;
        int ls = lr[p] >> 7;
        int b = lr[p] & 127;
        int s = part[p] ? (224 - 32 * c + ls) : (32 * c + ls);
        g[p] = b * SS + s;
    }

    if (tid < 2 * WW) {
        int p = tid / WW, w = tid % WW;
        cid_sh[p][w] = cidx[g[p] * WW + w];
    }
    if (tid < 2) wid_sh[tid] = widx[g[tid]];
    for (int i = tid; i < 2 * CE * 24; i += 256) ((float*)ce_sh)[i] = 0.f;
    __syncthreads();

    for (int i = tid; i < 2 * WW * CE; i += 256) {
        int p = i / (WW * CE);
        int rem = i % (WW * CE);
        int w = rem / CE, ce = rem % CE;
        ce_sh[p][ce][w + 1] = ctab[cid_sh[p][w] * CE + ce];
    }
    for (int i = tid; i < 2 * WE; i += 256) {
        int p = i / WE, col = i % WE;
        embC[(size_t)(part[p] * CR + lr[p]) * DIN + col] =
            wtab[(size_t)wid_sh[p] * WE + col];
    }
    __syncthreads();

    const int p = tid >> 7;
    const int cc = tid & 127;
    if (cc < CC) {
        float acc[WW];
        #pragma unroll
        for (int w = 0; w < WW; w++) acc[w] = 0.f;
        for (int ce = 0; ce < CE; ce++) {
            float row[24];
            #pragma unroll
            for (int q = 0; q < 6; q++) {
                float4 v = *(const float4*)&ce_sh[p][ce][q * 4];
                row[q * 4 + 0] = v.x; row[q * 4 + 1] = v.y;
                row[q * 4 + 2] = v.z; row[q * 4 + 3] = v.w;
            }
            float c0 = convw[(cc * CE + ce) * 3 + 0];
            float c1 = convw[(cc * CE + ce) * 3 + 1];
            float c2 = convw[(cc * CE + ce) * 3 + 2];
            #pragma unroll
            for (int w = 0; w < WW; w++)
                acc[w] += c0 * row[w] + c1 * row[w + 1] + c2 * row[w + 2];
        }
        float bb = convb[cc];
        float m = 0.f;
        #pragma unroll
        for (int w = 0; w < WW; w++) {
            float v = acc[w] + bb;
            v = v > 0.f ? v : 0.f;
            m = v > m ? v : m;
        }
        embC[(size_t)(part[p] * CR + lr[p]) * DIN + WE + cc] = m;
    }
}

// ---------------- Kernel B: chunk input projection: gatesC(2048 x 4096) ----------------
__global__ __launch_bounds__(256) void k_projC(
    const float* __restrict__ ef, const float* __restrict__ eb,
    const float* __restrict__ wih_f, const float* __restrict__ wih_b,
    const float* __restrict__ bih_f, const float* __restrict__ bhh_f,
    const float* __restrict__ bih_b, const float* __restrict__ bhh_b,
    float* __restrict__ gatesC)
{
    __shared__ __align__(16) float As[8][132];
    __shared__ __align__(16) float Bs[8][132];
    const int tid = threadIdx.x;
    const int rt = blockIdx.x;   // 0..31
    const int jt = blockIdx.y;   // 0..15
    const int tx = tid & 15, ty = tid >> 4;
    const int lj = tid >> 1;
    const int kh = (tid & 1) * 4;

    float acc[8][8];
    #pragma unroll
    for (int i = 0; i < 8; i++)
        #pragma unroll
        for (int j = 0; j < 8; j++) acc[i][j] = 0.f;

    const int jg = jt * 128 + lj;
    const float* wsrc = (jg < 1024) ? wih_f : wih_b;
    const int jj = jg & 1023;
    const float* esrc = (jt >= 8) ? eb : ef;

    for (int k0 = 0; k0 < DIN; k0 += 8) {
        float4 av = *(const float4*)&wsrc[(size_t)jj * DIN + k0 + kh];
        float4 bv = *(const float4*)&esrc[(size_t)(rt * 128 + lj) * DIN + k0 + kh];
        __syncthreads();
        As[kh + 0][lj] = av.x; As[kh + 1][lj] = av.y; As[kh + 2][lj] = av.z; As[kh + 3][lj] = av.w;
        Bs[kh + 0][lj] = bv.x; Bs[kh + 1][lj] = bv.y; Bs[kh + 2][lj] = bv.z; Bs[kh + 3][lj] = bv.w;
        __syncthreads();
        #pragma unroll
        for (int kk = 0; kk < 8; kk++) {
            float4 a0 = *(const float4*)&As[kk][ty * 8];
            float4 a1 = *(const float4*)&As[kk][ty * 8 + 4];
            float4 b0 = *(const float4*)&Bs[kk][tx * 8];
            float4 b1 = *(const float4*)&Bs[kk][tx * 8 + 4];
            float aa[8] = {a0.x, a0.y, a0.z, a0.w, a1.x, a1.y, a1.z, a1.w};
            float bbv[8] = {b0.x, b0.y, b0.z, b0.w, b1.x, b1.y, b1.z, b1.w};
            #pragma unroll
            for (int i = 0; i < 8; i++)
                #pragma unroll
                for (int j = 0; j < 8; j++) acc[i][j] += aa[i] * bbv[j];
        }
    }

    #pragma unroll
    for (int i = 0; i < 8; i++) {
        int j = jt * 128 + ty * 8 + i;
        int dir = j >> 10;
        int jr = j & 1023;
        float bias = dir ? (bih_b[jr] + bhh_b[jr]) : (bih_f[jr] + bhh_f[jr]);
        size_t base = (size_t)j * CR + rt * 128 + tx * 8;
        float4 o0 = {acc[i][0] + bias, acc[i][1] + bias, acc[i][2] + bias, acc[i][3] + bias};
        float4 o1 = {acc[i][4] + bias, acc[i][5] + bias, acc[i][6] + bias, acc[i][7] + bias};
        *(float4*)&gatesC[base] = o0;
        *(float4*)&gatesC[base + 4] = o1;
    }
}

// ---------------- group barrier: 4 groups x 64 blocks, 2-level, parity-indexed ----------------
// bar layout (ints): [0..3] phase per gid; [8 .. 8+64) sub[par][gid][sg(8)]; [72 .. 80) mid[par][gid]
__device__ __forceinline__ void groupbar(int* bar, int gid, int kg, int par, int target)
{
    __threadfence();
    __syncthreads();
    if (threadIdx.x == 0) {
        int* sub = bar + 8 + (par * 4 + gid) * 8;
        int* mid = bar + 8 + 64 + par * 4;
        int sg = kg >> 3;
        int a = __hip_atomic_fetch_add(&sub[sg], 1, __ATOMIC_ACQ_REL, __HIP_MEMORY_SCOPE_AGENT);
        if (a == 7) {
            __hip_atomic_store(&sub[sg], 0, __ATOMIC_RELAXED, __HIP_MEMORY_SCOPE_AGENT);
            int m = __hip_atomic_fetch_add(&mid[gid], 1, __ATOMIC_ACQ_REL, __HIP_MEMORY_SCOPE_AGENT);
            if (m == 7) {
                __hip_atomic_store(&mid[gid], 0, __ATOMIC_RELAXED, __HIP_MEMORY_SCOPE_AGENT);
                __hip_atomic_store(&bar[gid], target, __ATOMIC_RELEASE, __HIP_MEMORY_SCOPE_AGENT);
            }
        }
        while (__hip_atomic_load(&bar[gid], __ATOMIC_ACQUIRE, __HIP_MEMORY_SCOPE_AGENT) < target) {
            __builtin_amdgcn_s_sleep(1);
        }
    }
    __syncthreads();
    __threadfence();
}

// ---------------- Kernel C: persistent chunk LSTM — 32 steps, one launch ----------------
// grid 256 = dir(2) x bg(2, 64 b each) x kg(64, 4 k-out each); block 256 thr = 4 waves.
// Dot phase: wave w handles k-in slice [w*64, w*64+64) for all 16 gate-rows (scalar weights).
// Finalize: thread (wave=kout, lane=b) owns one h/c element; c stays in a register all chunk.
__global__ __launch_bounds__(256, 1) void k_lstm32(
    const float* __restrict__ gatesC,
    const float* __restrict__ whh_f, const float* __restrict__ whh_b,
    float* __restrict__ hglob, float* __restrict__ cbuf, float* __restrict__ lstmC,
    int* __restrict__ bar, int c)
{
    __shared__ float psum[4][16][64];   // [wave][jo][b]
    const int tid = threadIdx.x;
    const int lane = tid & 63;
    const int wv = tid >> 6;
    const int blk = blockIdx.x;
    const int dir = blk >> 7;
    const int bg  = (blk >> 6) & 1;
    const int kg  = blk & 63;
    const int bglob = bg * 64 + lane;
    const int gid = dir * 2 + bg;
    const int kglob = kg * 4 + wv;      // this thread's output k (finalize role)

    const float* whh = dir ? whh_b : whh_f;
    const int kw = __builtin_amdgcn_readfirstlane(wv * 64);  // wave-uniform k-in base

    float c_reg = (c == 0) ? 0.f : cbuf[(dir * Hh + kglob) * BB + bglob];

    for (int tl = 0; tl < CH; tl++) {
        const int t = c * CH + tl;
        const int ls = dir ? (CH - 1 - tl) : tl;
        const int lr = ls * BB + bglob;

        // pre-gates for this thread's (kout, b) — issue early
        float q0 = gatesC[(size_t)((dir * 4 + 0) * Hh + kglob) * CR + lr];
        float q1 = gatesC[(size_t)((dir * 4 + 1) * Hh + kglob) * CR + lr];
        float q2 = gatesC[(size_t)((dir * 4 + 2) * Hh + kglob) * CR + lr];
        float q3 = gatesC[(size_t)((dir * 4 + 3) * Hh + kglob) * CR + lr];

        float acc[16];
        #pragma unroll
        for (int jo = 0; jo < 16; jo++) acc[jo] = 0.f;

        if (t > 0) {
            const float* hsrc = hglob + (size_t)(t & 1) * HGLOB_STRIDE
                                      + (size_t)dir * Hh * BB;
            float hreg[32], hreg2[32];
            #pragma unroll
            for (int i = 0; i < 32; i++) hreg[i]  = hsrc[(kw + i) * BB + bglob];
            #pragma unroll
            for (int i = 0; i < 32; i++) hreg2[i] = hsrc[(kw + 32 + i) * BB + bglob];
            #pragma unroll
            for (int jo = 0; jo < 16; jo++) {
                const int ggate = jo >> 2, ko = jo & 3;
                const float* wrow = whh + (size_t)(ggate * Hh + kg * 4 + ko) * Hh + kw;
                float a = 0.f;
                #pragma unroll
                for (int i = 0; i < 32; i++) a += wrow[i] * hreg[i];
                #pragma unroll
                for (int i = 0; i < 32; i++) a += wrow[32 + i] * hreg2[i];
                acc[jo] = a;
            }
        }

        #pragma unroll
        for (int jo = 0; jo < 16; jo++) psum[wv][jo][lane] = acc[jo];
        __syncthreads();

        // finalize: this thread's kout = wv, b = lane; jo = gate*4 + wv
        float g0 = q0, g1 = q1, g2 = q2, g3 = q3;
        #pragma unroll
        for (int w = 0; w < 4; w++) {
            g0 += psum[w][0 * 4 + wv][lane];
            g1 += psum[w][1 * 4 + wv][lane];
            g2 += psum[w][2 * 4 + wv][lane];
            g3 += psum[w][3 * 4 + wv][lane];
        }
        float si = 1.f / (1.f + expf(-g0));
        float sf = 1.f / (1.f + expf(-g1));
        float tg = tanhf(g2);
        float so = 1.f / (1.f + expf(-g3));
        c_reg = sf * c_reg + si * tg;
        float h_new = so * tanhf(c_reg);

        hglob[(size_t)((t + 1) & 1) * HGLOB_STRIDE + (dir * Hh + kglob) * BB + bglob] = h_new;
        lstmC[(size_t)(dir * Hh + kglob) * CR + lr] = h_new;

        if (tl < CH - 1) groupbar(bar, gid, kg, t & 1, t + 1);
    }
    cbuf[(dir * Hh + kglob) * BB + bglob] = c_reg;
}

// ---------------- Kernel D0: feats = bias; also zero the barrier state ----------------
__global__ __launch_bounds__(256) void k_feats_init(
    const float* __restrict__ h2b, float* __restrict__ feats, int* __restrict__ bar)
{
    int i = blockIdx.x * 256 + threadIdx.x;
    if (i < BS * TT) feats[i] = h2b[i % TT];
    if (blockIdx.x == 0 && threadIdx.x < 128) bar[threadIdx.x] = 0;
}

// ---------------- Kernel D: accumulate chunk's lstm h into feats ----------------
__global__ __launch_bounds__(256) void k_feats_acc(
    const float* __restrict__ lstmC,
    const float* __restrict__ h2w, float* __restrict__ feats, int c)
{
    __shared__ float ps[TT][128];
    const int part = blockIdx.x >> 5;
    const int ls = blockIdx.x & 31;
    const int b = threadIdx.x & 127;
    const int kh = threadIdx.x >> 7;
    const int s = part ? (224 - 32 * c + ls) : (32 * c + ls);
    const int r = s * BB + b;
    const int k0 = kh * 128;

    float acc[TT];
    #pragma unroll
    for (int t = 0; t < TT; t++) acc[t] = 0.f;
    for (int dk = 0; dk < 128; dk++) {
        float v = lstmC[(size_t)(part * Hh + k0 + dk) * CR + ls * BB + b];
        #pragma unroll
        for (int t = 0; t < TT; t++) acc[t] += v * h2w[t * HID + part * Hh + k0 + dk];
    }
    if (kh) {
        #pragma unroll
        for (int t = 0; t < TT; t++) ps[t][b] = acc[t];
    }
    __syncthreads();
    if (!kh) {
        #pragma unroll
        for (int t = 0; t < TT; t++)
            feats[(size_t)r * TT + t] += acc[t] + ps[t][b];
    }
}

// ---------------- Kernel E: Viterbi forward + backtrace, one wave per batch ----------------
__global__ __launch_bounds__(64) void k_viterbi(
    const float* __restrict__ feats,
    const int* __restrict__ mask, const float* __restrict__ trans,
    float* __restrict__ out)
{
    __shared__ unsigned char bp_sh[SS][TT];
    __shared__ int red[64];
    __shared__ int len_sh;
    const int b = blockIdx.x;
    const int tid = threadIdx.x;
    const int n = tid;

    int partial = 0;
    for (int s = tid; s < SS; s += 64) partial += mask[b * SS + s];
    red[tid] = partial;
    __syncthreads();
    if (tid == 0) {
        int L = 0;
        for (int i = 0; i < 64; i++) L += red[i];
        len_sh = L;
    }
    __syncthreads();
    const int len = len_sh;

    float tr[TT];
    float alpha = NEGV;
    if (n < TT) {
        #pragma unroll
        for (int p = 0; p < TT; p++) tr[p] = trans[p * TT + n];
        alpha = (n == START_TAG) ? 0.f : NEGV;
    }

    for (int s = 0; s < len; s++) {
        float feat = (n < TT) ? feats[(size_t)(s * BB + b) * TT + n] : 0.f;
        float best = -3.0e38f;
        int bpi = 0;
        #pragma unroll
        for (int p = 0; p < TT; p++) {
            float ap = __shfl(alpha, p, 64);
            float sc = (n < TT) ? ((ap + tr[p]) + feat) : -3.0e38f;
            if (sc > best) { best = sc; bpi = p; }
        }
        if (n < TT) {
            bp_sh[s][n] = (unsigned char)bpi;
            alpha = best;
        }
    }

    float term = (n < TT) ? (alpha + trans[STOP_TAG * TT + n]) : -3.0e38f;
    float bs = -3.0e38f;
    int bl = 0;
    #pragma unroll
    for (int p = 0; p < TT; p++) {
        float v = __shfl(term, p, 64);
        if (v > bs) { bs = v; bl = p; }
    }

    if (tid == 0) {
        out[b] = bs;
        int tag = bl;
        for (int s = SS - 1; s >= 0; s--) {
            float o;
            if (s < len) {
                o = (float)tag;
                tag = (int)bp_sh[s][tag];
            } else {
                o = (float)PAD_TAG;
            }
            out[BB + b * SS + s] = o;
        }
    }
}

extern "C" void kernel_launch(void* const* d_in, const int* in_sizes, int n_in,
                              void* d_out, int out_size, void* d_ws, size_t ws_size,
                              hipStream_t stream) {
    const int*   widx  = (const int*)d_in[0];
    const int*   cidx  = (const int*)d_in[1];
    const int*   mask  = (const int*)d_in[2];
    const float* wtab  = (const float*)d_in[3];
    const float* ctab  = (const float*)d_in[4];
    const float* convw = (const float*)d_in[5];
    const float* convb = (const float*)d_in[6];
    const float* wih_f = (const float*)d_in[7];
    const float* whh_f = (const float*)d_in[8];
    const float* bih_f = (const float*)d_in[9];
    const float* bhh_f = (const float*)d_in[10];
    const float* wih_b = (const float*)d_in[11];
    const float* whh_b = (const float*)d_in[12];
    const float* bih_b = (const float*)d_in[13];
    const float* bhh_b = (const float*)d_in[14];
    const float* h2w   = (const float*)d_in[15];
    const float* h2b   = (const float*)d_in[16];
    const float* trans = (const float*)d_in[17];

    const bool full = ws_size >= FULL_NEEDED_BYTES;  // constant per session
    float* ws = (float*)d_ws;
    float* emb    = ws;
    const size_t emb_fl = full ? (size_t)BS * DIN : (size_t)2 * CR * DIN;
    float* gatesC = emb + emb_fl;                    // 2048*4096
    float* lstmC  = gatesC + (size_t)2048 * CR;      // 512*4096
    float* feats  = lstmC + (size_t)HID * CR;        // 32768*12
    float* hglob  = feats + (size_t)BS * TT;         // 2 parities * 2 dir * 256 * 128
    float* cbuf   = hglob + (size_t)2 * HGLOB_STRIDE;// 2*256*128
    int*   bar    = (int*)(cbuf + (size_t)2 * Hh * BB);  // 128 ints

    hipLaunchKernelGGL(k_feats_init, dim3((BS * TT + 255) / 256), dim3(256), 0, stream,
                       h2b, feats, bar);
    if (full) {
        hipLaunchKernelGGL(k_embedF, dim3(BS / 2), dim3(256), 0, stream,
                           widx, cidx, wtab, ctab, convw, convb, emb);
    }
    for (int c = 0; c < NCH; c++) {
        if (!full) {
            hipLaunchKernelGGL(k_embedC, dim3(CR), dim3(256), 0, stream,
                               widx, cidx, wtab, ctab, convw, convb, emb, c);
        }
        const float* ef = full ? (emb + (size_t)(32 * c * BB) * DIN) : emb;
        const float* eb = full ? (emb + (size_t)((224 - 32 * c) * BB) * DIN)
                               : (emb + (size_t)CR * DIN);
        hipLaunchKernelGGL(k_projC, dim3(CR / 128, 16), dim3(256), 0, stream,
                           ef, eb, wih_f, wih_b, bih_f, bhh_f, bih_b, bhh_b, gatesC);
        hipLaunchKernelGGL(k_lstm32, dim3(256), dim3(256), 0, stream,
                           gatesC, whh_f, whh_b, hglob, cbuf, lstmC, bar, c);
        hipLaunchKernelGGL(k_feats_acc, dim3(64), dim3(256), 0, stream,
                           lstmC, h2w, feats, c);
    }
    hipLaunchKernelGGL(k_viterbi, dim3(BB), dim3(64), 0, stream, feats, mask, trans, (float*)d_out);
}

// Round 5
// 6610.435 us; speedup vs baseline: 2.5455x; 2.5455x over previous
//
#include <hip/hip_runtime.h>

#define BB 128
#define SS 256
#define WW 20
#define WE 300
#define CE 50
#define CC 100
#define DIN 400
#define HID 512
#define Hh 256
#define TT 12
#define START_TAG 9
#define STOP_TAG 10
#define PAD_TAG 11
#define NEGV (-10000.0f)
#define BS 32768   // BB*SS
#define CH 32      // timesteps per chunk
#define NCH 8      // SS/CH
#define CR 4096    // CH*BB rows per direction per chunk

// full-emb mode ws floats: emb 13107200 + gates 8388608 + lstm 2097152 + feats 393216
//                          + hbuf 131072 + cbuf 65536
#define FULL_NEEDED_BYTES 96731136ull

// ---------------- Kernel A-full: embed entire sequence, each position ONCE ----------------
__global__ __launch_bounds__(256) void k_embedF(
    const int* __restrict__ widx, const int* __restrict__ cidx,
    const float* __restrict__ wtab, const float* __restrict__ ctab,
    const float* __restrict__ convw, const float* __restrict__ convb,
    float* __restrict__ emb)
{
    __shared__ __align__(16) float ce_sh[2][CE][24];
    __shared__ int cid_sh[2][WW];
    __shared__ int wid_sh[2];
    const int tid = threadIdx.x;
    const int pl0 = blockIdx.x * 2;

    int g[2];
    #pragma unroll
    for (int p = 0; p < 2; p++) {
        int pl = pl0 + p;
        int s = pl >> 7, b = pl & 127;
        g[p] = b * SS + s;
    }

    if (tid < 2 * WW) {
        int p = tid / WW, w = tid % WW;
        cid_sh[p][w] = cidx[g[p] * WW + w];
    }
    if (tid < 2) wid_sh[tid] = widx[g[tid]];
    for (int i = tid; i < 2 * CE * 24; i += 256) ((float*)ce_sh)[i] = 0.f;
    __syncthreads();

    for (int i = tid; i < 2 * WW * CE; i += 256) {
        int p = i / (WW * CE);
        int rem = i % (WW * CE);
        int w = rem / CE, ce = rem % CE;
        ce_sh[p][ce][w + 1] = ctab[cid_sh[p][w] * CE + ce];
    }
    for (int i = tid; i < 2 * WE; i += 256) {
        int p = i / WE, col = i % WE;
        emb[(size_t)(pl0 + p) * DIN + col] = wtab[(size_t)wid_sh[p] * WE + col];
    }
    __syncthreads();

    const int p = tid >> 7;
    const int cc = tid & 127;
    if (cc < CC) {
        float acc[WW];
        #pragma unroll
        for (int w = 0; w < WW; w++) acc[w] = 0.f;
        for (int ce = 0; ce < CE; ce++) {
            float row[24];
            #pragma unroll
            for (int q = 0; q < 6; q++) {
                float4 v = *(const float4*)&ce_sh[p][ce][q * 4];
                row[q * 4 + 0] = v.x; row[q * 4 + 1] = v.y;
                row[q * 4 + 2] = v.z; row[q * 4 + 3] = v.w;
            }
            float c0 = convw[(cc * CE + ce) * 3 + 0];
            float c1 = convw[(cc * CE + ce) * 3 + 1];
            float c2 = convw[(cc * CE + ce) * 3 + 2];
            #pragma unroll
            for (int w = 0; w < WW; w++)
                acc[w] += c0 * row[w] + c1 * row[w + 1] + c2 * row[w + 2];
        }
        float bb = convb[cc];
        float m = 0.f;
        #pragma unroll
        for (int w = 0; w < WW; w++) {
            float v = acc[w] + bb;
            v = v > 0.f ? v : 0.f;
            m = v > m ? v : m;
        }
        emb[(size_t)(pl0 + p) * DIN + WE + cc] = m;
    }
}

// ---------------- Kernel A-chunk: fallback (embed chunk rows, both dir ranges) ----------------
__global__ __launch_bounds__(256) void k_embedC(
    const int* __restrict__ widx, const int* __restrict__ cidx,
    const float* __restrict__ wtab, const float* __restrict__ ctab,
    const float* __restrict__ convw, const float* __restrict__ convb,
    float* __restrict__ embC, int c)
{
    __shared__ __align__(16) float ce_sh[2][CE][24];
    __shared__ int cid_sh[2][WW];
    __shared__ int wid_sh[2];
    const int tid = threadIdx.x;
    const int pl0 = blockIdx.x * 2;

    int part[2], lr[2], g[2];
    #pragma unroll
    for (int p = 0; p < 2; p++) {
        int pl = pl0 + p;
        part[p] = pl >> 12;
        lr[p] = pl & 4095;
        int ls = lr[p] >> 7;
        int b = lr[p] & 127;
        int s = part[p] ? (224 - 32 * c + ls) : (32 * c + ls);
        g[p] = b * SS + s;
    }

    if (tid < 2 * WW) {
        int p = tid / WW, w = tid % WW;
        cid_sh[p][w] = cidx[g[p] * WW + w];
    }
    if (tid < 2) wid_sh[tid] = widx[g[tid]];
    for (int i = tid; i < 2 * CE * 24; i += 256) ((float*)ce_sh)[i] = 0.f;
    __syncthreads();

    for (int i = tid; i < 2 * WW * CE; i += 256) {
        int p = i / (WW * CE);
        int rem = i % (WW * CE);
        int w = rem / CE, ce = rem % CE;
        ce_sh[p][ce][w + 1] = ctab[cid_sh[p][w] * CE + ce];
    }
    for (int i = tid; i < 2 * WE; i += 256) {
        int p = i / WE, col = i % WE;
        embC[(size_t)(part[p] * CR + lr[p]) * DIN + col] =
            wtab[(size_t)wid_sh[p] * WE + col];
    }
    __syncthreads();

    const int p = tid >> 7;
    const int cc = tid & 127;
    if (cc < CC) {
        float acc[WW];
        #pragma unroll
        for (int w = 0; w < WW; w++) acc[w] = 0.f;
        for (int ce = 0; ce < CE; ce++) {
            float row[24];
            #pragma unroll
            for (int q = 0; q < 6; q++) {
                float4 v = *(const float4*)&ce_sh[p][ce][q * 4];
                row[q * 4 + 0] = v.x; row[q * 4 + 1] = v.y;
                row[q * 4 + 2] = v.z; row[q * 4 + 3] = v.w;
            }
            float c0 = convw[(cc * CE + ce) * 3 + 0];
            float c1 = convw[(cc * CE + ce) * 3 + 1];
            float c2 = convw[(cc * CE + ce) * 3 + 2];
            #pragma unroll
            for (int w = 0; w < WW; w++)
                acc[w] += c0 * row[w] + c1 * row[w + 1] + c2 * row[w + 2];
        }
        float bb = convb[cc];
        float m = 0.f;
        #pragma unroll
        for (int w = 0; w < WW; w++) {
            float v = acc[w] + bb;
            v = v > 0.f ? v : 0.f;
            m = v > m ? v : m;
        }
        embC[(size_t)(part[p] * CR + lr[p]) * DIN + WE + cc] = m;
    }
}

// ---------------- Kernel B: chunk input projection: gatesC(2048 x 4096) ----------------
__global__ __launch_bounds__(256) void k_projC(
    const float* __restrict__ ef, const float* __restrict__ eb,
    const float* __restrict__ wih_f, const float* __restrict__ wih_b,
    const float* __restrict__ bih_f, const float* __restrict__ bhh_f,
    const float* __restrict__ bih_b, const float* __restrict__ bhh_b,
    float* __restrict__ gatesC)
{
    __shared__ __align__(16) float As[8][132];
    __shared__ __align__(16) float Bs[8][132];
    const int tid = threadIdx.x;
    const int rt = blockIdx.x;   // 0..31
    const int jt = blockIdx.y;   // 0..15
    const int tx = tid & 15, ty = tid >> 4;
    const int lj = tid >> 1;
    const int kh = (tid & 1) * 4;

    float acc[8][8];
    #pragma unroll
    for (int i = 0; i < 8; i++)
        #pragma unroll
        for (int j = 0; j < 8; j++) acc[i][j] = 0.f;

    const int jg = jt * 128 + lj;
    const float* wsrc = (jg < 1024) ? wih_f : wih_b;
    const int jj = jg & 1023;
    const float* esrc = (jt >= 8) ? eb : ef;

    for (int k0 = 0; k0 < DIN; k0 += 8) {
        float4 av = *(const float4*)&wsrc[(size_t)jj * DIN + k0 + kh];
        float4 bv = *(const float4*)&esrc[(size_t)(rt * 128 + lj) * DIN + k0 + kh];
        __syncthreads();
        As[kh + 0][lj] = av.x; As[kh + 1][lj] = av.y; As[kh + 2][lj] = av.z; As[kh + 3][lj] = av.w;
        Bs[kh + 0][lj] = bv.x; Bs[kh + 1][lj] = bv.y; Bs[kh + 2][lj] = bv.z; Bs[kh + 3][lj] = bv.w;
        __syncthreads();
        #pragma unroll
        for (int kk = 0; kk < 8; kk++) {
            float4 a0 = *(const float4*)&As[kk][ty * 8];
            float4 a1 = *(const float4*)&As[kk][ty * 8 + 4];
            float4 b0 = *(const float4*)&Bs[kk][tx * 8];
            float4 b1 = *(const float4*)&Bs[kk][tx * 8 + 4];
            float aa[8] = {a0.x, a0.y, a0.z, a0.w, a1.x, a1.y, a1.z, a1.w};
            float bbv[8] = {b0.x, b0.y, b0.z, b0.w, b1.x, b1.y, b1.z, b1.w};
            #pragma unroll
            for (int i = 0; i < 8; i++)
                #pragma unroll
                for (int j = 0; j < 8; j++) acc[i][j] += aa[i] * bbv[j];
        }
    }

    #pragma unroll
    for (int i = 0; i < 8; i++) {
        int j = jt * 128 + ty * 8 + i;
        int dir = j >> 10;
        int jr = j & 1023;
        float bias = dir ? (bih_b[jr] + bhh_b[jr]) : (bih_f[jr] + bhh_f[jr]);
        size_t base = (size_t)j * CR + rt * 128 + tx * 8;
        float4 o0 = {acc[i][0] + bias, acc[i][1] + bias, acc[i][2] + bias, acc[i][3] + bias};
        float4 o1 = {acc[i][4] + bias, acc[i][5] + bias, acc[i][6] + bias, acc[i][7] + bias};
        *(float4*)&gatesC[base] = o0;
        *(float4*)&gatesC[base + 4] = o1;
    }
}

// ---------------- Kernel C: one LSTM step, traffic-optimal geometry ----------------
// grid 256 = dir(2) x kot(32, 8 kouts each) x bq(4, 32 b each); 256 thr = (ko 0..7, bb 0..31).
// Thread owns one (kout, b): all 4 gates accumulated in-registers over kin 0..255.
// Per-step traffic: weights 8 MB + h 8 MB total (vs 66 MB in round-3 k_step2).
// hbuf layout [par][dir][b][k] so h loads are float4 down kin.
__global__ __launch_bounds__(256) void k_step3(
    const float* __restrict__ gatesC,
    const float* __restrict__ whh_f, const float* __restrict__ whh_b,
    float* __restrict__ hbuf, float* __restrict__ cbuf, float* __restrict__ lstmC,
    int t)
{
    const int tid = threadIdx.x;
    const int bb = tid & 31;
    const int ko = tid >> 5;              // 0..7
    const int blk = blockIdx.x;
    const int dir = blk >> 7;
    const int kot = (blk >> 2) & 31;
    const int bq  = blk & 3;
    const int b   = bq * 32 + bb;
    const int kout = kot * 8 + ko;
    const int tl = t & (CH - 1);
    const int ls = dir ? (CH - 1 - tl) : tl;
    const int lr = ls * BB + b;
    const int jb = dir * 4 * Hh;

    // issue pre-gate + c_old loads early; latency hides under the dot loop
    float g0 = gatesC[(size_t)(jb + 0 * Hh + kout) * CR + lr];
    float g1 = gatesC[(size_t)(jb + 1 * Hh + kout) * CR + lr];
    float g2 = gatesC[(size_t)(jb + 2 * Hh + kout) * CR + lr];
    float g3 = gatesC[(size_t)(jb + 3 * Hh + kout) * CR + lr];
    float c_old = 0.f;
    if (t > 0) c_old = cbuf[(dir * Hh + kout) * BB + b];

    if (t > 0) {
        const float* whh = dir ? whh_b : whh_f;
        const float* w0 = whh + (size_t)(0 * Hh + kout) * Hh;
        const float* w1 = whh + (size_t)(1 * Hh + kout) * Hh;
        const float* w2 = whh + (size_t)(2 * Hh + kout) * Hh;
        const float* w3 = whh + (size_t)(3 * Hh + kout) * Hh;
        const float* hrow = hbuf + (size_t)(((t & 1) * 2 + dir) * BB + b) * Hh;
        #pragma unroll 4
        for (int kin = 0; kin < Hh; kin += 4) {
            float4 hv = *(const float4*)&hrow[kin];
            float4 wa = *(const float4*)&w0[kin];
            float4 wb = *(const float4*)&w1[kin];
            float4 wc = *(const float4*)&w2[kin];
            float4 wd = *(const float4*)&w3[kin];
            g0 += hv.x * wa.x + hv.y * wa.y + hv.z * wa.z + hv.w * wa.w;
            g1 += hv.x * wb.x + hv.y * wb.y + hv.z * wb.z + hv.w * wb.w;
            g2 += hv.x * wc.x + hv.y * wc.y + hv.z * wc.z + hv.w * wc.w;
            g3 += hv.x * wd.x + hv.y * wd.y + hv.z * wd.z + hv.w * wd.w;
        }
    }

    float si = 1.f / (1.f + expf(-g0));
    float sf = 1.f / (1.f + expf(-g1));
    float tg = tanhf(g2);
    float so = 1.f / (1.f + expf(-g3));
    float c_new = sf * c_old + si * tg;
    float h_new = so * tanhf(c_new);

    cbuf[(dir * Hh + kout) * BB + b] = c_new;
    hbuf[(size_t)((((t + 1) & 1) * 2 + dir) * BB + b) * Hh + kout] = h_new;
    lstmC[(size_t)(dir * Hh + kout) * CR + lr] = h_new;
}

// ---------------- Kernel D0: feats = bias ----------------
__global__ __launch_bounds__(256) void k_feats_init(
    const float* __restrict__ h2b, float* __restrict__ feats)
{
    int i = blockIdx.x * 256 + threadIdx.x;
    if (i < BS * TT) feats[i] = h2b[i % TT];
}

// ---------------- Kernel D: accumulate chunk's lstm h into feats ----------------
__global__ __launch_bounds__(256) void k_feats_acc(
    const float* __restrict__ lstmC,
    const float* __restrict__ h2w, float* __restrict__ feats, int c)
{
    __shared__ float ps[TT][128];
    const int part = blockIdx.x >> 5;
    const int ls = blockIdx.x & 31;
    const int b = threadIdx.x & 127;
    const int kh = threadIdx.x >> 7;
    const int s = part ? (224 - 32 * c + ls) : (32 * c + ls);
    const int r = s * BB + b;
    const int k0 = kh * 128;

    float acc[TT];
    #pragma unroll
    for (int t = 0; t < TT; t++) acc[t] = 0.f;
    for (int dk = 0; dk < 128; dk++) {
        float v = lstmC[(size_t)(part * Hh + k0 + dk) * CR + ls * BB + b];
        #pragma unroll
        for (int t = 0; t < TT; t++) acc[t] += v * h2w[t * HID + part * Hh + k0 + dk];
    }
    if (kh) {
        #pragma unroll
        for (int t = 0; t < TT; t++) ps[t][b] = acc[t];
    }
    __syncthreads();
    if (!kh) {
        #pragma unroll
        for (int t = 0; t < TT; t++)
            feats[(size_t)r * TT + t] += acc[t] + ps[t][b];
    }
}

// ---------------- Kernel E: Viterbi forward + backtrace, one wave per batch ----------------
__global__ __launch_bounds__(64) void k_viterbi(
    const float* __restrict__ feats,
    const int* __restrict__ mask, const float* __restrict__ trans,
    float* __restrict__ out)
{
    __shared__ unsigned char bp_sh[SS][TT];
    __shared__ int red[64];
    __shared__ int len_sh;
    const int b = blockIdx.x;
    const int tid = threadIdx.x;
    const int n = tid;

    int partial = 0;
    for (int s = tid; s < SS; s += 64) partial += mask[b * SS + s];
    red[tid] = partial;
    __syncthreads();
    if (tid == 0) {
        int L = 0;
        for (int i = 0; i < 64; i++) L += red[i];
        len_sh = L;
    }
    __syncthreads();
    const int len = len_sh;

    float tr[TT];
    float alpha = NEGV;
    if (n < TT) {
        #pragma unroll
        for (int p = 0; p < TT; p++) tr[p] = trans[p * TT + n];
        alpha = (n == START_TAG) ? 0.f : NEGV;
    }

    for (int s = 0; s < len; s++) {
        float feat = (n < TT) ? feats[(size_t)(s * BB + b) * TT + n] : 0.f;
        float best = -3.0e38f;
        int bpi = 0;
        #pragma unroll
        for (int p = 0; p < TT; p++) {
            float ap = __shfl(alpha, p, 64);
            float sc = (n < TT) ? ((ap + tr[p]) + feat) : -3.0e38f;
            if (sc > best) { best = sc; bpi = p; }
        }
        if (n < TT) {
            bp_sh[s][n] = (unsigned char)bpi;
            alpha = best;
        }
    }

    float term = (n < TT) ? (alpha + trans[STOP_TAG * TT + n]) : -3.0e38f;
    float bs = -3.0e38f;
    int bl = 0;
    #pragma unroll
    for (int p = 0; p < TT; p++) {
        float v = __shfl(term, p, 64);
        if (v > bs) { bs = v; bl = p; }
    }

    if (tid == 0) {
        out[b] = bs;
        int tag = bl;
        for (int s = SS - 1; s >= 0; s--) {
            float o;
            if (s < len) {
                o = (float)tag;
                tag = (int)bp_sh[s][tag];
            } else {
                o = (float)PAD_TAG;
            }
            out[BB + b * SS + s] = o;
        }
    }
}

extern "C" void kernel_launch(void* const* d_in, const int* in_sizes, int n_in,
                              void* d_out, int out_size, void* d_ws, size_t ws_size,
                              hipStream_t stream) {
    const int*   widx  = (const int*)d_in[0];
    const int*   cidx  = (const int*)d_in[1];
    const int*   mask  = (const int*)d_in[2];
    const float* wtab  = (const float*)d_in[3];
    const float* ctab  = (const float*)d_in[4];
    const float* convw = (const float*)d_in[5];
    const float* convb = (const float*)d_in[6];
    const float* wih_f = (const float*)d_in[7];
    const float* whh_f = (const float*)d_in[8];
    const float* bih_f = (const float*)d_in[9];
    const float* bhh_f = (const float*)d_in[10];
    const float* wih_b = (const float*)d_in[11];
    const float* whh_b = (const float*)d_in[12];
    const float* bih_b = (const float*)d_in[13];
    const float* bhh_b = (const float*)d_in[14];
    const float* h2w   = (const float*)d_in[15];
    const float* h2b   = (const float*)d_in[16];
    const float* trans = (const float*)d_in[17];

    const bool full = ws_size >= FULL_NEEDED_BYTES;  // constant per session
    float* ws = (float*)d_ws;
    float* emb    = ws;
    const size_t emb_fl = full ? (size_t)BS * DIN : (size_t)2 * CR * DIN;
    float* gatesC = emb + emb_fl;                    // 2048*4096
    float* lstmC  = gatesC + (size_t)2048 * CR;      // 512*4096
    float* feats  = lstmC + (size_t)HID * CR;        // 32768*12
    float* hbuf   = feats + (size_t)BS * TT;         // 2 par * 2 dir * 128 b * 256 k
    float* cbuf   = hbuf + (size_t)4 * Hh * BB;      // 2*256*128

    hipLaunchKernelGGL(k_feats_init, dim3((BS * TT + 255) / 256), dim3(256), 0, stream,
                       h2b, feats);
    if (full) {
        hipLaunchKernelGGL(k_embedF, dim3(BS / 2), dim3(256), 0, stream,
                           widx, cidx, wtab, ctab, convw, convb, emb);
    }
    for (int c = 0; c < NCH; c++) {
        if (!full) {
            hipLaunchKernelGGL(k_embedC, dim3(CR), dim3(256), 0, stream,
                               widx, cidx, wtab, ctab, convw, convb, emb, c);
        }
        const float* ef = full ? (emb + (size_t)(32 * c * BB) * DIN) : emb;
        const float* eb = full ? (emb + (size_t)((224 - 32 * c) * BB) * DIN)
                               : (emb + (size_t)CR * DIN);
        hipLaunchKernelGGL(k_projC, dim3(CR / 128, 16), dim3(256), 0, stream,
                           ef, eb, wih_f, wih_b, bih_f, bhh_f, bih_b, bhh_b, gatesC);
        for (int tl = 0; tl < CH; tl++) {
            hipLaunchKernelGGL(k_step3, dim3(256), dim3(256), 0, stream,
                               gatesC, whh_f, whh_b, hbuf, cbuf, lstmC, c * CH + tl);
        }
        hipLaunchKernelGGL(k_feats_acc, dim3(64), dim3(256), 0, stream,
                           lstmC, h2w, feats, c);
    }
    hipLaunchKernelGGL(k_viterbi, dim3(BB), dim3(64), 0, stream, feats, mask, trans, (float*)d_out);
}

// Round 6
// 4340.602 us; speedup vs baseline: 3.8766x; 1.5229x over previous
//
#include <hip/hip_runtime.h>

#define BB 128
#define SS 256
#define WW 20
#define WE 300
#define CE 50
#define CC 100
#define DIN 400
#define HID 512
#define Hh 256
#define TT 12
#define START_TAG 9
#define STOP_TAG 10
#define PAD_TAG 11
#define NEGV (-10000.0f)
#define BS 32768   // BB*SS
#define CH 32      // timesteps per chunk
#define NCH 8      // SS/CH
#define CR 4096    // CH*BB rows per direction per chunk

// full-emb mode ws floats: emb 13107200 + gates 8388608 + lstm 2097152 + feats 393216
//                          + hbuf 131072 + cbuf 65536
#define FULL_NEEDED_BYTES 96731136ull

// ---------------- Kernel A-full: embed entire sequence, each position ONCE ----------------
__global__ __launch_bounds__(256) void k_embedF(
    const int* __restrict__ widx, const int* __restrict__ cidx,
    const float* __restrict__ wtab, const float* __restrict__ ctab,
    const float* __restrict__ convw, const float* __restrict__ convb,
    float* __restrict__ emb)
{
    __shared__ __align__(16) float ce_sh[2][CE][24];
    __shared__ int cid_sh[2][WW];
    __shared__ int wid_sh[2];
    const int tid = threadIdx.x;
    const int pl0 = blockIdx.x * 2;

    int g[2];
    #pragma unroll
    for (int p = 0; p < 2; p++) {
        int pl = pl0 + p;
        int s = pl >> 7, b = pl & 127;
        g[p] = b * SS + s;
    }

    if (tid < 2 * WW) {
        int p = tid / WW, w = tid % WW;
        cid_sh[p][w] = cidx[g[p] * WW + w];
    }
    if (tid < 2) wid_sh[tid] = widx[g[tid]];
    for (int i = tid; i < 2 * CE * 24; i += 256) ((float*)ce_sh)[i] = 0.f;
    __syncthreads();

    for (int i = tid; i < 2 * WW * CE; i += 256) {
        int p = i / (WW * CE);
        int rem = i % (WW * CE);
        int w = rem / CE, ce = rem % CE;
        ce_sh[p][ce][w + 1] = ctab[cid_sh[p][w] * CE + ce];
    }
    for (int i = tid; i < 2 * WE; i += 256) {
        int p = i / WE, col = i % WE;
        emb[(size_t)(pl0 + p) * DIN + col] = wtab[(size_t)wid_sh[p] * WE + col];
    }
    __syncthreads();

    const int p = tid >> 7;
    const int cc = tid & 127;
    if (cc < CC) {
        float acc[WW];
        #pragma unroll
        for (int w = 0; w < WW; w++) acc[w] = 0.f;
        for (int ce = 0; ce < CE; ce++) {
            float row[24];
            #pragma unroll
            for (int q = 0; q < 6; q++) {
                float4 v = *(const float4*)&ce_sh[p][ce][q * 4];
                row[q * 4 + 0] = v.x; row[q * 4 + 1] = v.y;
                row[q * 4 + 2] = v.z; row[q * 4 + 3] = v.w;
            }
            float c0 = convw[(cc * CE + ce) * 3 + 0];
            float c1 = convw[(cc * CE + ce) * 3 + 1];
            float c2 = convw[(cc * CE + ce) * 3 + 2];
            #pragma unroll
            for (int w = 0; w < WW; w++)
                acc[w] += c0 * row[w] + c1 * row[w + 1] + c2 * row[w + 2];
        }
        float bb = convb[cc];
        float m = 0.f;
        #pragma unroll
        for (int w = 0; w < WW; w++) {
            float v = acc[w] + bb;
            v = v > 0.f ? v : 0.f;
            m = v > m ? v : m;
        }
        emb[(size_t)(pl0 + p) * DIN + WE + cc] = m;
    }
}

// ---------------- Kernel A-chunk: fallback (embed chunk rows, both dir ranges) ----------------
__global__ __launch_bounds__(256) void k_embedC(
    const int* __restrict__ widx, const int* __restrict__ cidx,
    const float* __restrict__ wtab, const float* __restrict__ ctab,
    const float* __restrict__ convw, const float* __restrict__ convb,
    float* __restrict__ embC, int c)
{
    __shared__ __align__(16) float ce_sh[2][CE][24];
    __shared__ int cid_sh[2][WW];
    __shared__ int wid_sh[2];
    const int tid = threadIdx.x;
    const int pl0 = blockIdx.x * 2;

    int part[2], lr[2], g[2];
    #pragma unroll
    for (int p = 0; p < 2; p++) {
        int pl = pl0 + p;
        part[p] = pl >> 12;
        lr[p] = pl & 4095;
        int ls = lr[p] >> 7;
        int b = lr[p] & 127;
        int s = part[p] ? (224 - 32 * c + ls) : (32 * c + ls);
        g[p] = b * SS + s;
    }

    if (tid < 2 * WW) {
        int p = tid / WW, w = tid % WW;
        cid_sh[p][w] = cidx[g[p] * WW + w];
    }
    if (tid < 2) wid_sh[tid] = widx[g[tid]];
    for (int i = tid; i < 2 * CE * 24; i += 256) ((float*)ce_sh)[i] = 0.f;
    __syncthreads();

    for (int i = tid; i < 2 * WW * CE; i += 256) {
        int p = i / (WW * CE);
        int rem = i % (WW * CE);
        int w = rem / CE, ce = rem % CE;
        ce_sh[p][ce][w + 1] = ctab[cid_sh[p][w] * CE + ce];
    }
    for (int i = tid; i < 2 * WE; i += 256) {
        int p = i / WE, col = i % WE;
        embC[(size_t)(part[p] * CR + lr[p]) * DIN + col] =
            wtab[(size_t)wid_sh[p] * WE + col];
    }
    __syncthreads();

    const int p = tid >> 7;
    const int cc = tid & 127;
    if (cc < CC) {
        float acc[WW];
        #pragma unroll
        for (int w = 0; w < WW; w++) acc[w] = 0.f;
        for (int ce = 0; ce < CE; ce++) {
            float row[24];
            #pragma unroll
            for (int q = 0; q < 6; q++) {
                float4 v = *(const float4*)&ce_sh[p][ce][q * 4];
                row[q * 4 + 0] = v.x; row[q * 4 + 1] = v.y;
                row[q * 4 + 2] = v.z; row[q * 4 + 3] = v.w;
            }
            float c0 = convw[(cc * CE + ce) * 3 + 0];
            float c1 = convw[(cc * CE + ce) * 3 + 1];
            float c2 = convw[(cc * CE + ce) * 3 + 2];
            #pragma unroll
            for (int w = 0; w < WW; w++)
                acc[w] += c0 * row[w] + c1 * row[w + 1] + c2 * row[w + 2];
        }
        float bb = convb[cc];
        float m = 0.f;
        #pragma unroll
        for (int w = 0; w < WW; w++) {
            float v = acc[w] + bb;
            v = v > 0.f ? v : 0.f;
            m = v > m ? v : m;
        }
        embC[(size_t)(part[p] * CR + lr[p]) * DIN + WE + cc] = m;
    }
}

// ---------------- Kernel B: chunk input projection: gatesC(2048 x 4096) ----------------
__global__ __launch_bounds__(256) void k_projC(
    const float* __restrict__ ef, const float* __restrict__ eb,
    const float* __restrict__ wih_f, const float* __restrict__ wih_b,
    const float* __restrict__ bih_f, const float* __restrict__ bhh_f,
    const float* __restrict__ bih_b, const float* __restrict__ bhh_b,
    float* __restrict__ gatesC)
{
    __shared__ __align__(16) float As[8][132];
    __shared__ __align__(16) float Bs[8][132];
    const int tid = threadIdx.x;
    const int rt = blockIdx.x;   // 0..31
    const int jt = blockIdx.y;   // 0..15
    const int tx = tid & 15, ty = tid >> 4;
    const int lj = tid >> 1;
    const int kh = (tid & 1) * 4;

    float acc[8][8];
    #pragma unroll
    for (int i = 0; i < 8; i++)
        #pragma unroll
        for (int j = 0; j < 8; j++) acc[i][j] = 0.f;

    const int jg = jt * 128 + lj;
    const float* wsrc = (jg < 1024) ? wih_f : wih_b;
    const int jj = jg & 1023;
    const float* esrc = (jt >= 8) ? eb : ef;

    for (int k0 = 0; k0 < DIN; k0 += 8) {
        float4 av = *(const float4*)&wsrc[(size_t)jj * DIN + k0 + kh];
        float4 bv = *(const float4*)&esrc[(size_t)(rt * 128 + lj) * DIN + k0 + kh];
        __syncthreads();
        As[kh + 0][lj] = av.x; As[kh + 1][lj] = av.y; As[kh + 2][lj] = av.z; As[kh + 3][lj] = av.w;
        Bs[kh + 0][lj] = bv.x; Bs[kh + 1][lj] = bv.y; Bs[kh + 2][lj] = bv.z; Bs[kh + 3][lj] = bv.w;
        __syncthreads();
        #pragma unroll
        for (int kk = 0; kk < 8; kk++) {
            float4 a0 = *(const float4*)&As[kk][ty * 8];
            float4 a1 = *(const float4*)&As[kk][ty * 8 + 4];
            float4 b0 = *(const float4*)&Bs[kk][tx * 8];
            float4 b1 = *(const float4*)&Bs[kk][tx * 8 + 4];
            float aa[8] = {a0.x, a0.y, a0.z, a0.w, a1.x, a1.y, a1.z, a1.w};
            float bbv[8] = {b0.x, b0.y, b0.z, b0.w, b1.x, b1.y, b1.z, b1.w};
            #pragma unroll
            for (int i = 0; i < 8; i++)
                #pragma unroll
                for (int j = 0; j < 8; j++) acc[i][j] += aa[i] * bbv[j];
        }
    }

    #pragma unroll
    for (int i = 0; i < 8; i++) {
        int j = jt * 128 + ty * 8 + i;
        int dir = j >> 10;
        int jr = j & 1023;
        float bias = dir ? (bih_b[jr] + bhh_b[jr]) : (bih_f[jr] + bhh_f[jr]);
        size_t base = (size_t)j * CR + rt * 128 + tx * 8;
        float4 o0 = {acc[i][0] + bias, acc[i][1] + bias, acc[i][2] + bias, acc[i][3] + bias};
        float4 o1 = {acc[i][4] + bias, acc[i][5] + bias, acc[i][6] + bias, acc[i][7] + bias};
        *(float4*)&gatesC[base] = o0;
        *(float4*)&gatesC[base + 4] = o1;
    }
}

// ---------------- Kernel C: one LSTM step (k_stepT) ----------------
// grid 512 = dir(2) x kt(64: 4 kouts) x bq(4: 32 b); block 256 thr (4 waves); 2 blocks/CU.
// Stage h[256k x 32b] in LDS (coalesced float4); each thread dots 2 of the block's 16
// gate-rows over all 256 k (weights float4, wave-broadcast, L2-resident); results via
// 2KB LDS tile; 128 threads finalize gates + c/h, all global accesses coalesced.
__global__ __launch_bounds__(256) void k_stepT(
    const float* __restrict__ gatesC,
    const float* __restrict__ whh_f, const float* __restrict__ whh_b,
    float* __restrict__ hbuf, float* __restrict__ cbuf, float* __restrict__ lstmC,
    int t)
{
    __shared__ __align__(16) float h_sh[Hh][32];    // 32 KB
    __shared__ float res_sh[16][32];                // 2 KB
    const int tid = threadIdx.x;
    const int blk = blockIdx.x;
    const int dir = blk >> 8;
    const int kt  = (blk >> 2) & 63;
    const int bq  = blk & 3;
    const int tl  = t & (CH - 1);
    const int ls  = dir ? (CH - 1 - tl) : tl;

    // finalize-role preloads (issue before the dot loop; latency hidden under it)
    const int ko = (tid >> 5) & 3;   // for tid<128: 0..3
    const int bbf = tid & 31;
    const int koutf = kt * 4 + ko;
    const int bf = bq * 32 + bbf;
    const int lrf = ls * BB + bf;
    const int jb = dir * 4 * Hh;
    float q0 = 0.f, q1 = 0.f, q2 = 0.f, q3 = 0.f, c_old = 0.f;
    if (tid < 128) {
        q0 = gatesC[(size_t)(jb + 0 * Hh + koutf) * CR + lrf];
        q1 = gatesC[(size_t)(jb + 1 * Hh + koutf) * CR + lrf];
        q2 = gatesC[(size_t)(jb + 2 * Hh + koutf) * CR + lrf];
        q3 = gatesC[(size_t)(jb + 3 * Hh + koutf) * CR + lrf];
        if (t > 0) c_old = cbuf[(dir * Hh + koutf) * BB + bf];
    }

    if (t > 0) {
        // stage h slab slice: hbuf[par][dir][k][b], rows of 32 b
        const float* hsrc = hbuf + (size_t)((t & 1) * 2 + dir) * Hh * BB + bq * 32;
        const int kk0 = tid >> 3;          // 0..31
        const int bo4 = (tid & 7) * 4;     // 0..28
        #pragma unroll
        for (int it = 0; it < 8; it++) {
            int k = it * 32 + kk0;
            float4 v = *(const float4*)&hsrc[(size_t)k * BB + bo4];
            *(float4*)&h_sh[k][bo4] = v;
        }
        __syncthreads();

        // dot: thread handles gate-rows jj and jj+8 for batch-lane bb
        const int bb = tid & 31;
        const int jj = tid >> 5;           // 0..7
        const float* whh = dir ? whh_b : whh_f;
        const int jr1 = jj, jr2 = jj + 8;  // jr: g = jr>>2, kl = jr&3
        const float* w1 = whh + (size_t)((jr1 >> 2) * Hh + kt * 4 + (jr1 & 3)) * Hh;
        const float* w2 = whh + (size_t)((jr2 >> 2) * Hh + kt * 4 + (jr2 & 3)) * Hh;
        float a1 = 0.f, a2 = 0.f;
        #pragma unroll 8
        for (int k = 0; k < Hh; k += 4) {
            float4 wv1 = *(const float4*)&w1[k];
            float4 wv2 = *(const float4*)&w2[k];
            float h0 = h_sh[k + 0][bb];
            float h1 = h_sh[k + 1][bb];
            float h2 = h_sh[k + 2][bb];
            float h3 = h_sh[k + 3][bb];
            a1 += wv1.x * h0 + wv1.y * h1 + wv1.z * h2 + wv1.w * h3;
            a2 += wv2.x * h0 + wv2.y * h1 + wv2.z * h2 + wv2.w * h3;
        }
        res_sh[jr1][bb] = a1;
        res_sh[jr2][bb] = a2;
    }
    __syncthreads();   // t is grid-uniform: no divergence hazard

    if (tid < 128) {
        float g0 = q0, g1 = q1, g2 = q2, g3 = q3;
        if (t > 0) {
            g0 += res_sh[0 * 4 + ko][bbf];
            g1 += res_sh[1 * 4 + ko][bbf];
            g2 += res_sh[2 * 4 + ko][bbf];
            g3 += res_sh[3 * 4 + ko][bbf];
        }
        float si = 1.f / (1.f + expf(-g0));
        float sf = 1.f / (1.f + expf(-g1));
        float tg = tanhf(g2);
        float so = 1.f / (1.f + expf(-g3));
        float c_new = sf * c_old + si * tg;
        float h_new = so * tanhf(c_new);

        cbuf[(dir * Hh + koutf) * BB + bf] = c_new;
        hbuf[(size_t)(((t + 1) & 1) * 2 + dir) * Hh * BB + (size_t)koutf * BB + bf] = h_new;
        lstmC[(size_t)(dir * Hh + koutf) * CR + lrf] = h_new;
    }
}

// ---------------- Kernel D0: feats = bias ----------------
__global__ __launch_bounds__(256) void k_feats_init(
    const float* __restrict__ h2b, float* __restrict__ feats)
{
    int i = blockIdx.x * 256 + threadIdx.x;
    if (i < BS * TT) feats[i] = h2b[i % TT];
}

// ---------------- Kernel D: accumulate chunk's lstm h into feats ----------------
__global__ __launch_bounds__(256) void k_feats_acc(
    const float* __restrict__ lstmC,
    const float* __restrict__ h2w, float* __restrict__ feats, int c)
{
    __shared__ float ps[TT][128];
    const int part = blockIdx.x >> 5;
    const int ls = blockIdx.x & 31;
    const int b = threadIdx.x & 127;
    const int kh = threadIdx.x >> 7;
    const int s = part ? (224 - 32 * c + ls) : (32 * c + ls);
    const int r = s * BB + b;
    const int k0 = kh * 128;

    float acc[TT];
    #pragma unroll
    for (int t = 0; t < TT; t++) acc[t] = 0.f;
    for (int dk = 0; dk < 128; dk++) {
        float v = lstmC[(size_t)(part * Hh + k0 + dk) * CR + ls * BB + b];
        #pragma unroll
        for (int t = 0; t < TT; t++) acc[t] += v * h2w[t * HID + part * Hh + k0 + dk];
    }
    if (kh) {
        #pragma unroll
        for (int t = 0; t < TT; t++) ps[t][b] = acc[t];
    }
    __syncthreads();
    if (!kh) {
        #pragma unroll
        for (int t = 0; t < TT; t++)
            feats[(size_t)r * TT + t] += acc[t] + ps[t][b];
    }
}

// ---------------- Kernel E: Viterbi forward + backtrace, one wave per batch ----------------
__global__ __launch_bounds__(64) void k_viterbi(
    const float* __restrict__ feats,
    const int* __restrict__ mask, const float* __restrict__ trans,
    float* __restrict__ out)
{
    __shared__ unsigned char bp_sh[SS][TT];
    __shared__ int red[64];
    __shared__ int len_sh;
    const int b = blockIdx.x;
    const int tid = threadIdx.x;
    const int n = tid;

    int partial = 0;
    for (int s = tid; s < SS; s += 64) partial += mask[b * SS + s];
    red[tid] = partial;
    __syncthreads();
    if (tid == 0) {
        int L = 0;
        for (int i = 0; i < 64; i++) L += red[i];
        len_sh = L;
    }
    __syncthreads();
    const int len = len_sh;

    float tr[TT];
    float alpha = NEGV;
    if (n < TT) {
        #pragma unroll
        for (int p = 0; p < TT; p++) tr[p] = trans[p * TT + n];
        alpha = (n == START_TAG) ? 0.f : NEGV;
    }

    for (int s = 0; s < len; s++) {
        float feat = (n < TT) ? feats[(size_t)(s * BB + b) * TT + n] : 0.f;
        float best = -3.0e38f;
        int bpi = 0;
        #pragma unroll
        for (int p = 0; p < TT; p++) {
            float ap = __shfl(alpha, p, 64);
            float sc = (n < TT) ? ((ap + tr[p]) + feat) : -3.0e38f;
            if (sc > best) { best = sc; bpi = p; }
        }
        if (n < TT) {
            bp_sh[s][n] = (unsigned char)bpi;
            alpha = best;
        }
    }

    float term = (n < TT) ? (alpha + trans[STOP_TAG * TT + n]) : -3.0e38f;
    float bs = -3.0e38f;
    int bl = 0;
    #pragma unroll
    for (int p = 0; p < TT; p++) {
        float v = __shfl(term, p, 64);
        if (v > bs) { bs = v; bl = p; }
    }

    if (tid == 0) {
        out[b] = bs;
        int tag = bl;
        for (int s = SS - 1; s >= 0; s--) {
            float o;
            if (s < len) {
                o = (float)tag;
                tag = (int)bp_sh[s][tag];
            } else {
                o = (float)PAD_TAG;
            }
            out[BB + b * SS + s] = o;
        }
    }
}

extern "C" void kernel_launch(void* const* d_in, const int* in_sizes, int n_in,
                              void* d_out, int out_size, void* d_ws, size_t ws_size,
                              hipStream_t stream) {
    const int*   widx  = (const int*)d_in[0];
    const int*   cidx  = (const int*)d_in[1];
    const int*   mask  = (const int*)d_in[2];
    const float* wtab  = (const float*)d_in[3];
    const float* ctab  = (const float*)d_in[4];
    const float* convw = (const float*)d_in[5];
    const float* convb = (const float*)d_in[6];
    const float* wih_f = (const float*)d_in[7];
    const float* whh_f = (const float*)d_in[8];
    const float* bih_f = (const float*)d_in[9];
    const float* bhh_f = (const float*)d_in[10];
    const float* wih_b = (const float*)d_in[11];
    const float* whh_b = (const float*)d_in[12];
    const float* bih_b = (const float*)d_in[13];
    const float* bhh_b = (const float*)d_in[14];
    const float* h2w   = (const float*)d_in[15];
    const float* h2b   = (const float*)d_in[16];
    const float* trans = (const float*)d_in[17];

    const bool full = ws_size >= FULL_NEEDED_BYTES;  // constant per session
    float* ws = (float*)d_ws;
    float* emb    = ws;
    const size_t emb_fl = full ? (size_t)BS * DIN : (size_t)2 * CR * DIN;
    float* gatesC = emb + emb_fl;                    // 2048*4096
    float* lstmC  = gatesC + (size_t)2048 * CR;      // 512*4096
    float* feats  = lstmC + (size_t)HID * CR;        // 32768*12
    float* hbuf   = feats + (size_t)BS * TT;         // 2 par * 2 dir * 256 k * 128 b
    float* cbuf   = hbuf + (size_t)4 * Hh * BB;      // 2*256*128

    hipLaunchKernelGGL(k_feats_init, dim3((BS * TT + 255) / 256), dim3(256), 0, stream,
                       h2b, feats);
    if (full) {
        hipLaunchKernelGGL(k_embedF, dim3(BS / 2), dim3(256), 0, stream,
                           widx, cidx, wtab, ctab, convw, convb, emb);
    }
    for (int c = 0; c < NCH; c++) {
        if (!full) {
            hipLaunchKernelGGL(k_embedC, dim3(CR), dim3(256), 0, stream,
                               widx, cidx, wtab, ctab, convw, convb, emb, c);
        }
        const float* ef = full ? (emb + (size_t)(32 * c * BB) * DIN) : emb;
        const float* eb = full ? (emb + (size_t)((224 - 32 * c) * BB) * DIN)
                               : (emb + (size_t)CR * DIN);
        hipLaunchKernelGGL(k_projC, dim3(CR / 128, 16), dim3(256), 0, stream,
                           ef, eb, wih_f, wih_b, bih_f, bhh_f, bih_b, bhh_b, gatesC);
        for (int tl = 0; tl < CH; tl++) {
            hipLaunchKernelGGL(k_stepT, dim3(512), dim3(256), 0, stream,
                               gatesC, whh_f, whh_b, hbuf, cbuf, lstmC, c * CH + tl);
        }
        hipLaunchKernelGGL(k_feats_acc, dim3(64), dim3(256), 0, stream,
                           lstmC, h2w, feats, c);
    }
    hipLaunchKernelGGL(k_viterbi, dim3(BB), dim3(64), 0, stream, feats, mask, trans, (float*)d_out);
}

// Round 7
// 2858.936 us; speedup vs baseline: 5.8857x; 1.5183x over previous
//
#include <hip/hip_runtime.h>

#define BB 128
#define SS 256
#define WW 20
#define WE 300
#define CE 50
#define CC 100
#define DIN 400
#define KP 416      // DIN padded to 13*32 for MFMA K-loop
#define HID 512
#define Hh 256
#define TT 12
#define START_TAG 9
#define STOP_TAG 10
#define PAD_TAG 11
#define NEGV (-10000.0f)
#define BS 32768   // BB*SS
#define CH 32      // timesteps per chunk
#define NCH 8      // SS/CH
#define CR 4096    // CH*BB rows per direction per chunk

typedef __attribute__((ext_vector_type(8))) short short8;
typedef __attribute__((ext_vector_type(4))) float floatx4;

// byte sizes (all multiples of 256)
#define SZ_EMB_FULL  27262976ull   // 32768*416*2
#define SZ_EMB_CHUNK  6815744ull   // 8192*416*2
#define SZ_WB         1703936ull   // 2048*416*2
#define SZ_BIAS          8192ull   // 2048*4
#define SZ_GATES     33554432ull   // 2048*4096*4
#define SZ_LSTM       8388608ull   // 512*4096*4
#define SZ_FEATS      1572864ull   // 32768*12*4
#define SZ_HBUF        524288ull   // 4*256*128*4
#define SZ_CBUF        262144ull   // 2*256*128*4
#define FULL_NEEDED_BYTES (SZ_EMB_FULL + SZ_WB + SZ_BIAS + SZ_GATES + SZ_LSTM + SZ_FEATS + SZ_HBUF + SZ_CBUF)

__device__ __forceinline__ unsigned short f2bf(float x) {
    unsigned int u = __builtin_bit_cast(unsigned int, x);
    unsigned int r = (u + 0x7FFFu + ((u >> 16) & 1u)) >> 16;
    return (unsigned short)r;
}

// ---------------- Kernel W: pack W_ih (both dirs) to bf16 [2048][416] + fp32 bias ----------------
__global__ __launch_bounds__(256) void k_w2b(
    const float* __restrict__ wih_f, const float* __restrict__ wih_b,
    const float* __restrict__ bih_f, const float* __restrict__ bhh_f,
    const float* __restrict__ bih_b, const float* __restrict__ bhh_b,
    unsigned short* __restrict__ wB, float* __restrict__ biasC)
{
    int idx = blockIdx.x * 256 + threadIdx.x;
    if (idx < 2048 * KP) {
        int j = idx / KP;
        int col = idx - j * KP;
        const float* src = (j < 1024) ? wih_f : wih_b;
        int jr = j & 1023;
        wB[idx] = (col < DIN) ? f2bf(src[jr * DIN + col]) : 0;
    }
    if (idx < 2048) {
        int jr = idx & 1023;
        biasC[idx] = (idx < 1024) ? (bih_f[jr] + bhh_f[jr]) : (bih_b[jr] + bhh_b[jr]);
    }
}

// ---------------- Kernel A-full: embed entire sequence (bf16 out, K-padded) ----------------
__global__ __launch_bounds__(256) void k_embedF(
    const int* __restrict__ widx, const int* __restrict__ cidx,
    const float* __restrict__ wtab, const float* __restrict__ ctab,
    const float* __restrict__ convw, const float* __restrict__ convb,
    unsigned short* __restrict__ embB)
{
    __shared__ __align__(16) float ce_sh[2][CE][24];
    __shared__ int cid_sh[2][WW];
    __shared__ int wid_sh[2];
    const int tid = threadIdx.x;
    const int pl0 = blockIdx.x * 2;

    int g[2];
    #pragma unroll
    for (int p = 0; p < 2; p++) {
        int pl = pl0 + p;
        int s = pl >> 7, b = pl & 127;
        g[p] = b * SS + s;
    }

    if (tid < 2 * WW) {
        int p = tid / WW, w = tid % WW;
        cid_sh[p][w] = cidx[g[p] * WW + w];
    }
    if (tid < 2) wid_sh[tid] = widx[g[tid]];
    for (int i = tid; i < 2 * CE * 24; i += 256) ((float*)ce_sh)[i] = 0.f;
    __syncthreads();

    for (int i = tid; i < 2 * WW * CE; i += 256) {
        int p = i / (WW * CE);
        int rem = i % (WW * CE);
        int w = rem / CE, ce = rem % CE;
        ce_sh[p][ce][w + 1] = ctab[cid_sh[p][w] * CE + ce];
    }
    for (int i = tid; i < 2 * WE; i += 256) {
        int p = i / WE, col = i % WE;
        embB[(size_t)(pl0 + p) * KP + col] = f2bf(wtab[(size_t)wid_sh[p] * WE + col]);
    }
    for (int i = tid; i < 2 * (KP - DIN); i += 256) {
        int p = i / (KP - DIN), col = DIN + i % (KP - DIN);
        embB[(size_t)(pl0 + p) * KP + col] = 0;
    }
    __syncthreads();

    const int p = tid >> 7;
    const int cc = tid & 127;
    if (cc < CC) {
        float acc[WW];
        #pragma unroll
        for (int w = 0; w < WW; w++) acc[w] = 0.f;
        for (int ce = 0; ce < CE; ce++) {
            float row[24];
            #pragma unroll
            for (int q = 0; q < 6; q++) {
                float4 v = *(const float4*)&ce_sh[p][ce][q * 4];
                row[q * 4 + 0] = v.x; row[q * 4 + 1] = v.y;
                row[q * 4 + 2] = v.z; row[q * 4 + 3] = v.w;
            }
            float c0 = convw[(cc * CE + ce) * 3 + 0];
            float c1 = convw[(cc * CE + ce) * 3 + 1];
            float c2 = convw[(cc * CE + ce) * 3 + 2];
            #pragma unroll
            for (int w = 0; w < WW; w++)
                acc[w] += c0 * row[w] + c1 * row[w + 1] + c2 * row[w + 2];
        }
        float bb = convb[cc];
        float m = 0.f;
        #pragma unroll
        for (int w = 0; w < WW; w++) {
            float v = acc[w] + bb;
            v = v > 0.f ? v : 0.f;
            m = v > m ? v : m;
        }
        embB[(size_t)(pl0 + p) * KP + WE + cc] = f2bf(m);
    }
}

// ---------------- Kernel A-chunk: fallback (embed chunk rows, both dir ranges, bf16) ----------------
__global__ __launch_bounds__(256) void k_embedC(
    const int* __restrict__ widx, const int* __restrict__ cidx,
    const float* __restrict__ wtab, const float* __restrict__ ctab,
    const float* __restrict__ convw, const float* __restrict__ convb,
    unsigned short* __restrict__ embB, int c)
{
    __shared__ __align__(16) float ce_sh[2][CE][24];
    __shared__ int cid_sh[2][WW];
    __shared__ int wid_sh[2];
    const int tid = threadIdx.x;
    const int pl0 = blockIdx.x * 2;

    int part[2], lr[2], g[2];
    #pragma unroll
    for (int p = 0; p < 2; p++) {
        int pl = pl0 + p;
        part[p] = pl >> 12;
        lr[p] = pl & 4095;
        int ls = lr[p] >> 7;
        int b = lr[p] & 127;
        int s = part[p] ? (224 - 32 * c + ls) : (32 * c + ls);
        g[p] = b * SS + s;
    }

    if (tid < 2 * WW) {
        int p = tid / WW, w = tid % WW;
        cid_sh[p][w] = cidx[g[p] * WW + w];
    }
    if (tid < 2) wid_sh[tid] = widx[g[tid]];
    for (int i = tid; i < 2 * CE * 24; i += 256) ((float*)ce_sh)[i] = 0.f;
    __syncthreads();

    for (int i = tid; i < 2 * WW * CE; i += 256) {
        int p = i / (WW * CE);
        int rem = i % (WW * CE);
        int w = rem / CE, ce = rem % CE;
        ce_sh[p][ce][w + 1] = ctab[cid_sh[p][w] * CE + ce];
    }
    for (int i = tid; i < 2 * WE; i += 256) {
        int p = i / WE, col = i % WE;
        embB[(size_t)(part[p] * CR + lr[p]) * KP + col] =
            f2bf(wtab[(size_t)wid_sh[p] * WE + col]);
    }
    for (int i = tid; i < 2 * (KP - DIN); i += 256) {
        int p = i / (KP - DIN), col = DIN + i % (KP - DIN);
        embB[(size_t)(part[p] * CR + lr[p]) * KP + col] = 0;
    }
    __syncthreads();

    const int p = tid >> 7;
    const int cc = tid & 127;
    if (cc < CC) {
        float acc[WW];
        #pragma unroll
        for (int w = 0; w < WW; w++) acc[w] = 0.f;
        for (int ce = 0; ce < CE; ce++) {
            float row[24];
            #pragma unroll
            for (int q = 0; q < 6; q++) {
                float4 v = *(const float4*)&ce_sh[p][ce][q * 4];
                row[q * 4 + 0] = v.x; row[q * 4 + 1] = v.y;
                row[q * 4 + 2] = v.z; row[q * 4 + 3] = v.w;
            }
            float c0 = convw[(cc * CE + ce) * 3 + 0];
            float c1 = convw[(cc * CE + ce) * 3 + 1];
            float c2 = convw[(cc * CE + ce) * 3 + 2];
            #pragma unroll
            for (int w = 0; w < WW; w++)
                acc[w] += c0 * row[w] + c1 * row[w + 1] + c2 * row[w + 2];
        }
        float bb = convb[cc];
        float m = 0.f;
        #pragma unroll
        for (int w = 0; w < WW; w++) {
            float v = acc[w] + bb;
            v = v > 0.f ? v : 0.f;
            m = v > m ? v : m;
        }
        embB[(size_t)(part[p] * CR + lr[p]) * KP + WE + cc] = f2bf(m);
    }
}

// ---------------- Kernel B: bf16 MFMA input projection: gatesC(2048 x 4096) ----------------
// C[j][r] = sum_k W[j][k]*emb[r][k] (+bias).  16x16x32 bf16 MFMA, 128x128 tile,
// 4 waves in 2x2, 4x4 frags each.  A-layout [m=lane&15][k=quad*8+j],
// C-layout col=lane&15, row=quad*4+reg  [verified mappings, guide §3].
__global__ __launch_bounds__(256) void k_projB(
    const unsigned short* __restrict__ ef, const unsigned short* __restrict__ eb,
    const unsigned short* __restrict__ wB, const float* __restrict__ biasC,
    float* __restrict__ gatesC)
{
    __shared__ __align__(16) unsigned short Wt[128 * 40];
    __shared__ __align__(16) unsigned short Et[128 * 40];
    const int tid = threadIdx.x;
    const int rt = blockIdx.x;   // 0..31
    const int jt = blockIdx.y;   // 0..15
    const unsigned short* esrc = (jt >= 8) ? eb : ef;

    const int row = tid >> 1;          // 0..127
    const int half = tid & 1;          // k-half of 32-k tile
    const int lane = tid & 63;
    const int wv = tid >> 6;
    const int wm = wv >> 1, wn = wv & 1;
    const int fr = lane & 15, quad = lane >> 4;

    floatx4 acc[4][4];
    #pragma unroll
    for (int i = 0; i < 4; i++)
        #pragma unroll
        for (int j = 0; j < 4; j++) acc[i][j] = (floatx4){0.f, 0.f, 0.f, 0.f};

    const unsigned short* wrow = wB + (size_t)(jt * 128 + row) * KP + half * 16;
    const unsigned short* erow = esrc + (size_t)(rt * 128 + row) * KP + half * 16;

    for (int kt = 0; kt < 13; kt++) {
        int4 wv0 = *(const int4*)(wrow + kt * 32);
        int4 wv1 = *(const int4*)(wrow + kt * 32 + 8);
        int4 ev0 = *(const int4*)(erow + kt * 32);
        int4 ev1 = *(const int4*)(erow + kt * 32 + 8);
        __syncthreads();
        *(int4*)&Wt[row * 40 + half * 16]     = wv0;
        *(int4*)&Wt[row * 40 + half * 16 + 8] = wv1;
        *(int4*)&Et[row * 40 + half * 16]     = ev0;
        *(int4*)&Et[row * 40 + half * 16 + 8] = ev1;
        __syncthreads();

        short8 af[4], bf[4];
        #pragma unroll
        for (int fi = 0; fi < 4; fi++)
            af[fi] = *(const short8*)&Wt[(wm * 64 + fi * 16 + fr) * 40 + quad * 8];
        #pragma unroll
        for (int fj = 0; fj < 4; fj++)
            bf[fj] = *(const short8*)&Et[(wn * 64 + fj * 16 + fr) * 40 + quad * 8];
        #pragma unroll
        for (int fi = 0; fi < 4; fi++)
            #pragma unroll
            for (int fj = 0; fj < 4; fj++)
                acc[fi][fj] = __builtin_amdgcn_mfma_f32_16x16x32_bf16(
                    af[fi], bf[fj], acc[fi][fj], 0, 0, 0);
    }

    // bias per (fi, reg): j depends only on fi/quad/reg
    float bias[4][4];
    #pragma unroll
    for (int fi = 0; fi < 4; fi++)
        #pragma unroll
        for (int reg = 0; reg < 4; reg++)
            bias[fi][reg] = biasC[jt * 128 + wm * 64 + fi * 16 + quad * 4 + reg];

    #pragma unroll
    for (int fi = 0; fi < 4; fi++) {
        #pragma unroll
        for (int fj = 0; fj < 4; fj++) {
            int rg = rt * 128 + wn * 64 + fj * 16 + fr;
            int jg = jt * 128 + wm * 64 + fi * 16 + quad * 4;
            #pragma unroll
            for (int reg = 0; reg < 4; reg++)
                gatesC[(size_t)(jg + reg) * CR + rg] = acc[fi][fj][reg] + bias[fi][reg];
        }
    }
}

// ---------------- Kernel C: one LSTM step (k_step2, proven round-3 version) ----------------
// grid 512 = dir*256+kg; thr 256 = (kh,b). Weights wave-uniform -> s_load; h coalesced.
__global__ __launch_bounds__(256) void k_step2(
    const float* __restrict__ gatesC,
    const float* __restrict__ whh_f, const float* __restrict__ whh_b,
    float* __restrict__ hbuf, float* __restrict__ cbuf, float* __restrict__ lstmC,
    int t)
{
    __shared__ float psum[4][128];
    const int tid = threadIdx.x;
    const int b = tid & 127;
    const int kh = tid >> 7;
    const int blk = blockIdx.x;
    const int dir = blk >> 8;
    const int kg = blk & 255;
    const int tl = t & (CH - 1);
    const int lr = (dir ? (CH - 1 - tl) : tl) * BB + b;

    float q0 = 0.f, q1 = 0.f, q2 = 0.f, q3 = 0.f, c_old = 0.f;
    const int jb = dir * 1024;
    if (kh == 0) {
        q0 = gatesC[(size_t)(jb + 0 * Hh + kg) * CR + lr];
        q1 = gatesC[(size_t)(jb + 1 * Hh + kg) * CR + lr];
        q2 = gatesC[(size_t)(jb + 2 * Hh + kg) * CR + lr];
        q3 = gatesC[(size_t)(jb + 3 * Hh + kg) * CR + lr];
        if (t > 0) c_old = cbuf[(size_t)(dir * Hh + kg) * BB + b];
    }

    float g0 = 0.f, g1 = 0.f, g2 = 0.f, g3 = 0.f;
    if (t > 0) {
        const float* whh = dir ? whh_b : whh_f;
        const int koff = __builtin_amdgcn_readfirstlane(kh * 128);
        const float* w0 = whh + (size_t)(0 * Hh + kg) * Hh + koff;
        const float* w1 = whh + (size_t)(1 * Hh + kg) * Hh + koff;
        const float* w2 = whh + (size_t)(2 * Hh + kg) * Hh + koff;
        const float* w3 = whh + (size_t)(3 * Hh + kg) * Hh + koff;
        const int par = t & 1;
        const float* hsrc = hbuf + (size_t)((par * 2 + dir) * Hh + koff) * BB;
        #pragma unroll 4
        for (int kk = 0; kk < 128; kk += 4) {
            float h0 = hsrc[(kk + 0) * BB + b];
            float h1 = hsrc[(kk + 1) * BB + b];
            float h2 = hsrc[(kk + 2) * BB + b];
            float h3 = hsrc[(kk + 3) * BB + b];
            float4 wa = *(const float4*)&w0[kk];
            float4 wb = *(const float4*)&w1[kk];
            float4 wc = *(const float4*)&w2[kk];
            float4 wd = *(const float4*)&w3[kk];
            g0 += h0 * wa.x + h1 * wa.y + h2 * wa.z + h3 * wa.w;
            g1 += h0 * wb.x + h1 * wb.y + h2 * wb.z + h3 * wb.w;
            g2 += h0 * wc.x + h1 * wc.y + h2 * wc.z + h3 * wc.w;
            g3 += h0 * wd.x + h1 * wd.y + h2 * wd.z + h3 * wd.w;
        }
    }

    if (kh) {
        psum[0][b] = g0; psum[1][b] = g1; psum[2][b] = g2; psum[3][b] = g3;
    }
    __syncthreads();
    if (!kh) {
        g0 = (q0 + g0) + psum[0][b];
        g1 = (q1 + g1) + psum[1][b];
        g2 = (q2 + g2) + psum[2][b];
        g3 = (q3 + g3) + psum[3][b];

        float si = 1.f / (1.f + expf(-g0));
        float sf = 1.f / (1.f + expf(-g1));
        float tg = tanhf(g2);
        float so = 1.f / (1.f + expf(-g3));
        float c_new = sf * c_old + si * tg;
        float h_new = so * tanhf(c_new);

        cbuf[(size_t)(dir * Hh + kg) * BB + b] = c_new;
        const int parn = (t + 1) & 1;
        hbuf[(size_t)((parn * 2 + dir) * Hh + kg) * BB + b] = h_new;
        lstmC[(size_t)(dir * Hh + kg) * CR + lr] = h_new;
    }
}

// ---------------- Kernel D0: feats = bias ----------------
__global__ __launch_bounds__(256) void k_feats_init(
    const float* __restrict__ h2b, float* __restrict__ feats)
{
    int i = blockIdx.x * 256 + threadIdx.x;
    if (i < BS * TT) feats[i] = h2b[i % TT];
}

// ---------------- Kernel D: accumulate chunk's lstm h into feats ----------------
__global__ __launch_bounds__(256) void k_feats_acc(
    const float* __restrict__ lstmC,
    const float* __restrict__ h2w, float* __restrict__ feats, int c)
{
    __shared__ float ps[TT][128];
    const int part = blockIdx.x >> 5;
    const int ls = blockIdx.x & 31;
    const int b = threadIdx.x & 127;
    const int kh = threadIdx.x >> 7;
    const int s = part ? (224 - 32 * c + ls) : (32 * c + ls);
    const int r = s * BB + b;
    const int k0 = kh * 128;

    float acc[TT];
    #pragma unroll
    for (int t = 0; t < TT; t++) acc[t] = 0.f;
    for (int dk = 0; dk < 128; dk++) {
        float v = lstmC[(size_t)(part * Hh + k0 + dk) * CR + ls * BB + b];
        #pragma unroll
        for (int t = 0; t < TT; t++) acc[t] += v * h2w[t * HID + part * Hh + k0 + dk];
    }
    if (kh) {
        #pragma unroll
        for (int t = 0; t < TT; t++) ps[t][b] = acc[t];
    }
    __syncthreads();
    if (!kh) {
        #pragma unroll
        for (int t = 0; t < TT; t++)
            feats[(size_t)r * TT + t] += acc[t] + ps[t][b];
    }
}

// ---------------- Kernel E: Viterbi forward + backtrace, one wave per batch ----------------
__global__ __launch_bounds__(64) void k_viterbi(
    const float* __restrict__ feats,
    const int* __restrict__ mask, const float* __restrict__ trans,
    float* __restrict__ out)
{
    __shared__ unsigned char bp_sh[SS][TT];
    __shared__ int red[64];
    __shared__ int len_sh;
    const int b = blockIdx.x;
    const int tid = threadIdx.x;
    const int n = tid;

    int partial = 0;
    for (int s = tid; s < SS; s += 64) partial += mask[b * SS + s];
    red[tid] = partial;
    __syncthreads();
    if (tid == 0) {
        int L = 0;
        for (int i = 0; i < 64; i++) L += red[i];
        len_sh = L;
    }
    __syncthreads();
    const int len = len_sh;

    float tr[TT];
    float alpha = NEGV;
    if (n < TT) {
        #pragma unroll
        for (int p = 0; p < TT; p++) tr[p] = trans[p * TT + n];
        alpha = (n == START_TAG) ? 0.f : NEGV;
    }

    for (int s = 0; s < len; s++) {
        float feat = (n < TT) ? feats[(size_t)(s * BB + b) * TT + n] : 0.f;
        float best = -3.0e38f;
        int bpi = 0;
        #pragma unroll
        for (int p = 0; p < TT; p++) {
            float ap = __shfl(alpha, p, 64);
            float sc = (n < TT) ? ((ap + tr[p]) + feat) : -3.0e38f;
            if (sc > best) { best = sc; bpi = p; }
        }
        if (n < TT) {
            bp_sh[s][n] = (unsigned char)bpi;
            alpha = best;
        }
    }

    float term = (n < TT) ? (alpha + trans[STOP_TAG * TT + n]) : -3.0e38f;
    float bs = -3.0e38f;
    int bl = 0;
    #pragma unroll
    for (int p = 0; p < TT; p++) {
        float v = __shfl(term, p, 64);
        if (v > bs) { bs = v; bl = p; }
    }

    if (tid == 0) {
        out[b] = bs;
        int tag = bl;
        for (int s = SS - 1; s >= 0; s--) {
            float o;
            if (s < len) {
                o = (float)tag;
                tag = (int)bp_sh[s][tag];
            } else {
                o = (float)PAD_TAG;
            }
            out[BB + b * SS + s] = o;
        }
    }
}

extern "C" void kernel_launch(void* const* d_in, const int* in_sizes, int n_in,
                              void* d_out, int out_size, void* d_ws, size_t ws_size,
                              hipStream_t stream) {
    const int*   widx  = (const int*)d_in[0];
    const int*   cidx  = (const int*)d_in[1];
    const int*   mask  = (const int*)d_in[2];
    const float* wtab  = (const float*)d_in[3];
    const float* ctab  = (const float*)d_in[4];
    const float* convw = (const float*)d_in[5];
    const float* convb = (const float*)d_in[6];
    const float* wih_f = (const float*)d_in[7];
    const float* whh_f = (const float*)d_in[8];
    const float* bih_f = (const float*)d_in[9];
    const float* bhh_f = (const float*)d_in[10];
    const float* wih_b = (const float*)d_in[11];
    const float* whh_b = (const float*)d_in[12];
    const float* bih_b = (const float*)d_in[13];
    const float* bhh_b = (const float*)d_in[14];
    const float* h2w   = (const float*)d_in[15];
    const float* h2b   = (const float*)d_in[16];
    const float* trans = (const float*)d_in[17];

    const bool full = ws_size >= FULL_NEEDED_BYTES;  // constant per session
    char* base = (char*)d_ws;
    const size_t emb_sz = full ? SZ_EMB_FULL : SZ_EMB_CHUNK;
    unsigned short* embB = (unsigned short*)base;
    unsigned short* wB   = (unsigned short*)(base + emb_sz);
    float* biasC  = (float*)(base + emb_sz + SZ_WB);
    float* gatesC = (float*)(base + emb_sz + SZ_WB + SZ_BIAS);
    float* lstmC  = (float*)(base + emb_sz + SZ_WB + SZ_BIAS + SZ_GATES);
    float* feats  = (float*)(base + emb_sz + SZ_WB + SZ_BIAS + SZ_GATES + SZ_LSTM);
    float* hbuf   = (float*)(base + emb_sz + SZ_WB + SZ_BIAS + SZ_GATES + SZ_LSTM + SZ_FEATS);
    float* cbuf   = (float*)(base + emb_sz + SZ_WB + SZ_BIAS + SZ_GATES + SZ_LSTM + SZ_FEATS + SZ_HBUF);

    hipLaunchKernelGGL(k_feats_init, dim3((BS * TT + 255) / 256), dim3(256), 0, stream,
                       h2b, feats);
    hipLaunchKernelGGL(k_w2b, dim3((2048 * KP + 255) / 256), dim3(256), 0, stream,
                       wih_f, wih_b, bih_f, bhh_f, bih_b, bhh_b, wB, biasC);
    if (full) {
        hipLaunchKernelGGL(k_embedF, dim3(BS / 2), dim3(256), 0, stream,
                           widx, cidx, wtab, ctab, convw, convb, embB);
    }
    for (int c = 0; c < NCH; c++) {
        if (!full) {
            hipLaunchKernelGGL(k_embedC, dim3(CR), dim3(256), 0, stream,
                               widx, cidx, wtab, ctab, convw, convb, embB, c);
        }
        const unsigned short* ef = full ? (embB + (size_t)(32 * c * BB) * KP) : embB;
        const unsigned short* eb = full ? (embB + (size_t)((224 - 32 * c) * BB) * KP)
                                        : (embB + (size_t)CR * KP);
        hipLaunchKernelGGL(k_projB, dim3(32, 16), dim3(256), 0, stream,
                           ef, eb, wB, biasC, gatesC);
        for (int tl = 0; tl < CH; tl++) {
            hipLaunchKernelGGL(k_step2, dim3(512), dim3(256), 0, stream,
                               gatesC, whh_f, whh_b, hbuf, cbuf, lstmC, c * CH + tl);
        }
        hipLaunchKernelGGL(k_feats_acc, dim3(64), dim3(256), 0, stream,
                           lstmC, h2w, feats, c);
    }
    hipLaunchKernelGGL(k_viterbi, dim3(BB), dim3(64), 0, stream, feats, mask, trans, (float*)d_out);
}